// Round 1
// baseline (101.104 us; speedup 1.0000x reference)
//
#include <hip/hip_runtime.h>
#include <math.h>

#define N 512
#define D 256

__global__ void init_out(float* out) { out[0] = 0.0f; }

__global__ __launch_bounds__(256) void rnc_row_kernel(
    const float* __restrict__ features,  // [256, 2, 256]
    const float* __restrict__ labels,    // [256, 1]
    float* __restrict__ out)
{
    const int i = blockIdx.x;   // row 0..511
    const int t = threadIdx.x;  // 0..255

    __shared__ float  sh_fi[D];       // f[i][:]
    __shared__ float2 sh_le[N];       // {ld_j, exp_j} (exp_i = 0 drops diagonal)
    __shared__ float  sh_logit[N];
    __shared__ float  sh_red[4];

    // f[i][d] = features[(i%256)*512 + (i/256)*256 + d]
    const float* fi = features + (size_t)(i & 255) * 512 + (size_t)(i >> 8) * 256;
    sh_fi[t] = fi[t];
    __syncthreads();

    const float lab_i = labels[i & 255];

    // each thread computes sq / logit / exp / ld for j = t and j = t+256
    #pragma unroll
    for (int jj = 0; jj < 2; ++jj) {
        const int j = t + jj * 256;
        const float* fj = features + (size_t)(j & 255) * 512 + (size_t)(j >> 8) * 256;
        float acc = 0.0f;
        #pragma unroll 4
        for (int d = 0; d < D; d += 4) {
            float4 v = *reinterpret_cast<const float4*>(fj + d);
            float d0 = sh_fi[d + 0] - v.x;
            float d1 = sh_fi[d + 1] - v.y;
            float d2 = sh_fi[d + 2] - v.z;
            float d3 = sh_fi[d + 3] - v.w;
            acc += d0 * d0 + d1 * d1 + d2 * d2 + d3 * d3;
        }
        // logits_max over a row is exactly 0 (diagonal), so no shift needed
        float norm  = (acc > 0.0f) ? sqrtf(acc) : 0.0f;
        float logit = -norm * 0.5f;                 // TEMP = 2
        sh_logit[j] = logit;
        float e = (j == i) ? 0.0f : expf(logit);    // zero exp excludes diagonal j
        sh_le[j] = make_float2(fabsf(lab_i - labels[j & 255]), e);
    }
    __syncthreads();

    // neg_k = sum_{j != i} [ld_j >= ld_k] * exp_j   (exp_i = 0 handles j == i)
    const int   k0 = t, k1 = t + 256;
    const float ldk0 = sh_le[k0].x;
    const float ldk1 = sh_le[k1].x;
    float neg0 = 0.0f, neg1 = 0.0f;
    #pragma unroll 8
    for (int j = 0; j < N; ++j) {
        float2 le = sh_le[j];   // broadcast read: conflict-free
        neg0 += (le.x >= ldk0) ? le.y : 0.0f;
        neg1 += (le.x >= ldk1) ? le.y : 0.0f;
    }

    float partial = 0.0f;
    if (k0 != i) partial += sh_logit[k0] - logf(neg0);
    if (k1 != i) partial += sh_logit[k1] - logf(neg1);

    // block reduction: butterfly within wave (64 lanes), then across 4 waves
    #pragma unroll
    for (int off = 32; off > 0; off >>= 1)
        partial += __shfl_down(partial, off, 64);
    const int wave = t >> 6;
    if ((t & 63) == 0) sh_red[wave] = partial;
    __syncthreads();
    if (t == 0) {
        float s = sh_red[0] + sh_red[1] + sh_red[2] + sh_red[3];
        atomicAdd(out, s * (-1.0f / ((float)N * (float)(N - 1))));
    }
}

extern "C" void kernel_launch(void* const* d_in, const int* in_sizes, int n_in,
                              void* d_out, int out_size, void* d_ws, size_t ws_size,
                              hipStream_t stream) {
    const float* features = (const float*)d_in[0];  // (256, 2, 256) fp32
    const float* labels   = (const float*)d_in[1];  // (256, 1) fp32
    float* out = (float*)d_out;                     // scalar fp32

    init_out<<<1, 1, 0, stream>>>(out);
    rnc_row_kernel<<<N, 256, 0, stream>>>(features, labels, out);
}

// Round 2
// 90.655 us; speedup vs baseline: 1.1153x; 1.1153x over previous
//
#include <hip/hip_runtime.h>
#include <math.h>

#define N 512
#define D 256
#define E2_OFF 4
#define WS_BYTES ((E2_OFF + 512 * 256) * sizeof(float))

__device__ __forceinline__ const float* frow(const float* F, int g) {
    // f[g][:] = features[(g%256), (g/256), :]
    return F + (size_t)(g & 255) * 512 + (size_t)(g >> 8) * 256;
}

// ---------------- Kernel A: pairwise dist -> logit-sum + E2 table ----------------
// block = 8 i-rows x 32 j-cols; 256 threads = 32 j x 8 d-slices (32 floats each)
__global__ __launch_bounds__(256) void rnc_dist_kernel(
    const float* __restrict__ F, const float* __restrict__ labels,
    float* __restrict__ ws)
{
    const int i0 = (blockIdx.x >> 4) * 8;
    const int t  = threadIdx.x;
    const int jl = t >> 3;     // 0..31 : j within block
    const int ds = t & 7;      // 0..7  : d-slice
    const int gj = (blockIdx.x & 15) * 32 + jl;

    __shared__ float sh_fi[8 * 256];
    __shared__ float sh_red[4];

    // stage 8 fi rows, XOR-swizzled so the 128B-stride reads are bank-conflict-free
    #pragma unroll
    for (int r = 0; r < 8; ++r) {
        const float* fi = frow(F, i0 + r);
        sh_fi[r * 256 + (t ^ ((t >> 3) & 28))] = fi[t];
    }

    // preload this thread's fj slice (32 floats) into registers
    const float* fj = frow(F, gj);
    float4 b[8];
    #pragma unroll
    for (int q = 0; q < 8; ++q)
        b[q] = *reinterpret_cast<const float4*>(fj + ds * 32 + q * 4);

    __syncthreads();

    float acc[8] = {0, 0, 0, 0, 0, 0, 0, 0};
    #pragma unroll
    for (int q = 0; q < 8; ++q) {
        const int eb = ds * 32 + ((q * 4) ^ (ds << 2));   // swizzled read addr
        #pragma unroll
        for (int r = 0; r < 8; ++r) {
            const float4 a = *reinterpret_cast<const float4*>(&sh_fi[r * 256 + eb]);
            const float d0 = a.x - b[q].x, d1 = a.y - b[q].y;
            const float d2 = a.z - b[q].z, d3 = a.w - b[q].w;
            acc[r] += d0 * d0 + d1 * d1 + d2 * d2 + d3 * d3;
        }
    }

    float slog = 0.0f;
    #pragma unroll
    for (int r = 0; r < 8; ++r) {
        float v = acc[r];
        v += __shfl_xor(v, 1, 64);
        v += __shfl_xor(v, 2, 64);
        v += __shfl_xor(v, 4, 64);
        if (ds == 0) {
            const int   gi    = i0 + r;
            const float logit = -0.5f * sqrtf(v);   // TEMP=2; row max is exactly 0
            slog += logit;                          // logit_ii = -0.0 contributes 0
            const float e = (gj == gi) ? 0.0f : expf(logit);
            atomicAdd(&ws[E2_OFF + gi * 256 + (gj & 255)], e);  // e_j + e_{j+256}
        }
    }

    // block-sum of logits (nonzero only on ds==0 lanes)
    #pragma unroll
    for (int off = 32; off > 0; off >>= 1)
        slog += __shfl_xor(slog, off, 64);
    if ((t & 63) == 0) sh_red[t >> 6] = slog;
    __syncthreads();
    if (t == 0)
        atomicAdd(&ws[0], sh_red[0] + sh_red[1] + sh_red[2] + sh_red[3]);
}

// ---------------- Kernel B: neg + log, folded to 256 columns ----------------
__global__ __launch_bounds__(256) void rnc_neg_kernel(
    const float* __restrict__ labels, float* __restrict__ ws)
{
    const int i = blockIdx.x;   // row 0..511
    const int t = threadIdx.x;  // k' = 0..255
    __shared__ float2 pr[256];  // {ld_j', E2[i][j']}
    __shared__ float  sh_red[4];

    const float lab_i = labels[i & 255];
    const float ldk   = fabsf(lab_i - labels[t]);
    pr[t] = make_float2(ldk, ws[E2_OFF + i * 256 + t]);
    __syncthreads();

    float ng0 = 0, ng1 = 0, ng2 = 0, ng3 = 0;
    #pragma unroll 8
    for (int j = 0; j < 256; j += 4) {
        const float2 p0 = pr[j + 0], p1 = pr[j + 1];
        const float2 p2 = pr[j + 2], p3 = pr[j + 3];
        ng0 += (p0.x >= ldk) ? p0.y : 0.0f;
        ng1 += (p1.x >= ldk) ? p1.y : 0.0f;
        ng2 += (p2.x >= ldk) ? p2.y : 0.0f;
        ng3 += (p3.x >= ldk) ? p3.y : 0.0f;
    }
    const float neg = (ng0 + ng1) + (ng2 + ng3);
    // k' = i&255 appears once among k != i (k=i excluded), all others twice
    const float m = (t == (i & 255)) ? 1.0f : 2.0f;
    float partial = m * logf(neg);

    #pragma unroll
    for (int off = 32; off > 0; off >>= 1)
        partial += __shfl_xor(partial, off, 64);
    if ((t & 63) == 0) sh_red[t >> 6] = partial;
    __syncthreads();
    if (t == 0)
        atomicAdd(&ws[1], sh_red[0] + sh_red[1] + sh_red[2] + sh_red[3]);
}

// ---------------- Kernel C: finalize ----------------
__global__ void rnc_final_kernel(const float* __restrict__ ws, float* __restrict__ out)
{
    // loss = (sum m*log(neg) - sum logit) / (n*(n-1))
    out[0] = (ws[1] - ws[0]) * (1.0f / (512.0f * 511.0f));
}

// ---------------- Fallback (round-1 fused kernel, needs no ws) ----------------
__global__ void init_out(float* out) { out[0] = 0.0f; }

__global__ __launch_bounds__(256) void rnc_row_kernel(
    const float* __restrict__ features, const float* __restrict__ labels,
    float* __restrict__ out)
{
    const int i = blockIdx.x;
    const int t = threadIdx.x;
    __shared__ float  sh_fi[D];
    __shared__ float2 sh_le[N];
    __shared__ float  sh_logit[N];
    __shared__ float  sh_red[4];

    const float* fi = frow(features, i);
    sh_fi[t] = fi[t];
    __syncthreads();
    const float lab_i = labels[i & 255];

    #pragma unroll
    for (int jj = 0; jj < 2; ++jj) {
        const int j = t + jj * 256;
        const float* fj = frow(features, j);
        float acc = 0.0f;
        #pragma unroll 4
        for (int d = 0; d < D; d += 4) {
            float4 v = *reinterpret_cast<const float4*>(fj + d);
            float d0 = sh_fi[d + 0] - v.x, d1 = sh_fi[d + 1] - v.y;
            float d2 = sh_fi[d + 2] - v.z, d3 = sh_fi[d + 3] - v.w;
            acc += d0 * d0 + d1 * d1 + d2 * d2 + d3 * d3;
        }
        float norm  = (acc > 0.0f) ? sqrtf(acc) : 0.0f;
        float logit = -norm * 0.5f;
        sh_logit[j] = logit;
        float e = (j == i) ? 0.0f : expf(logit);
        sh_le[j] = make_float2(fabsf(lab_i - labels[j & 255]), e);
    }
    __syncthreads();

    const int   k0 = t, k1 = t + 256;
    const float ldk0 = sh_le[k0].x, ldk1 = sh_le[k1].x;
    float neg0 = 0.0f, neg1 = 0.0f;
    #pragma unroll 8
    for (int j = 0; j < N; ++j) {
        float2 le = sh_le[j];
        neg0 += (le.x >= ldk0) ? le.y : 0.0f;
        neg1 += (le.x >= ldk1) ? le.y : 0.0f;
    }
    float partial = 0.0f;
    if (k0 != i) partial += sh_logit[k0] - logf(neg0);
    if (k1 != i) partial += sh_logit[k1] - logf(neg1);
    #pragma unroll
    for (int off = 32; off > 0; off >>= 1)
        partial += __shfl_down(partial, off, 64);
    if ((t & 63) == 0) sh_red[t >> 6] = partial;
    __syncthreads();
    if (t == 0)
        atomicAdd(out, (sh_red[0] + sh_red[1] + sh_red[2] + sh_red[3]) *
                       (-1.0f / ((float)N * (float)(N - 1))));
}

extern "C" void kernel_launch(void* const* d_in, const int* in_sizes, int n_in,
                              void* d_out, int out_size, void* d_ws, size_t ws_size,
                              hipStream_t stream) {
    const float* features = (const float*)d_in[0];  // (256, 2, 256) fp32
    const float* labels   = (const float*)d_in[1];  // (256, 1) fp32
    float* out = (float*)d_out;

    if (ws_size >= WS_BYTES) {
        float* ws = (float*)d_ws;
        hipMemsetAsync(d_ws, 0, WS_BYTES, stream);
        rnc_dist_kernel<<<1024, 256, 0, stream>>>(features, labels, ws);
        rnc_neg_kernel<<<512, 256, 0, stream>>>(labels, ws);
        rnc_final_kernel<<<1, 1, 0, stream>>>(ws, out);
    } else {
        init_out<<<1, 1, 0, stream>>>(out);
        rnc_row_kernel<<<N, 256, 0, stream>>>(features, labels, out);
    }
}

// Round 3
// 68.675 us; speedup vs baseline: 1.4722x; 1.3201x over previous
//
#include <hip/hip_runtime.h>
#include <math.h>

#define N 512
#define D 256
#define E_OFF 0                      // E table: 512*512 floats (e values, diag = 0)
#define PART_OFF (512 * 512)         // partials: 1024 (A: logit sums) + 512 (B: log terms)
#define WS_FLOATS (PART_OFF + 1024 + 512)
#define WS_BYTES (WS_FLOATS * sizeof(float))

__device__ __forceinline__ const float* frow(const float* F, int g) {
    // f[g][:] = features[(g%256), (g/256), :]
    return F + (size_t)(g & 255) * 512 + (size_t)(g >> 8) * 256;
}

// ---------------- Kernel A: pairwise dist -> E table + per-block logit sums ----
// 1024 blocks = 64 i-groups x 16 j-slices; 256 thr = 32 j-cols x 8 d-slices.
// After the 8-lane dot-product reduce, lane ds takes row r = ds, so all 64
// lanes of a wave do sqrt/exp/store (8 rows x 8 cols). No atomics.
__global__ __launch_bounds__(256) void rnc_dist_kernel(
    const float* __restrict__ F, float* __restrict__ ws)
{
    const int i0 = (blockIdx.x >> 4) * 8;
    const int t  = threadIdx.x;
    const int jl = t >> 3;     // 0..31 : j within block
    const int ds = t & 7;      // 0..7  : d-slice
    const int gj = (blockIdx.x & 15) * 32 + jl;

    __shared__ float sh_fi[8 * 256];
    __shared__ float sh_red[4];

    // stage 8 fi rows, XOR-swizzled (verified exact in round 2)
    #pragma unroll
    for (int r = 0; r < 8; ++r)
        sh_fi[r * 256 + (t ^ ((t >> 3) & 28))] = frow(F, i0 + r)[t];

    // preload this thread's fj slice (32 floats)
    const float* fj = frow(F, gj);
    float4 b[8];
    #pragma unroll
    for (int q = 0; q < 8; ++q)
        b[q] = *reinterpret_cast<const float4*>(fj + ds * 32 + q * 4);

    __syncthreads();

    float acc[8] = {0, 0, 0, 0, 0, 0, 0, 0};
    #pragma unroll
    for (int q = 0; q < 8; ++q) {
        const int eb = ds * 32 + ((q * 4) ^ (ds << 2));   // swizzled read addr
        #pragma unroll
        for (int r = 0; r < 8; ++r) {
            const float4 a = *reinterpret_cast<const float4*>(&sh_fi[r * 256 + eb]);
            const float d0 = a.x - b[q].x, d1 = a.y - b[q].y;
            const float d2 = a.z - b[q].z, d3 = a.w - b[q].w;
            acc[r] += d0 * d0 + d1 * d1 + d2 * d2 + d3 * d3;
        }
    }

    // reduce each row's partial dot across the 8-lane group
    #pragma unroll
    for (int r = 0; r < 8; ++r) {
        acc[r] += __shfl_xor(acc[r], 1, 64);
        acc[r] += __shfl_xor(acc[r], 2, 64);
        acc[r] += __shfl_xor(acc[r], 4, 64);
    }

    // lane ds owns row r = ds (static select chain -> cndmask, no scratch)
    float v = acc[0];
    v = (ds == 1) ? acc[1] : v;
    v = (ds == 2) ? acc[2] : v;
    v = (ds == 3) ? acc[3] : v;
    v = (ds == 4) ? acc[4] : v;
    v = (ds == 5) ? acc[5] : v;
    v = (ds == 6) ? acc[6] : v;
    v = (ds == 7) ? acc[7] : v;

    const int   gi    = i0 + ds;
    const float logit = -0.5f * sqrtf(v);            // TEMP=2; v_ii is exactly 0
    ws[E_OFF + gi * 512 + gj] = (gj == gi) ? 0.0f : expf(logit);

    // sum of logits over this block's 8x32 tile (diag contributes -0.0)
    float slog = logit;
    #pragma unroll
    for (int off = 32; off > 0; off >>= 1)
        slog += __shfl_xor(slog, off, 64);
    if ((t & 63) == 0) sh_red[t >> 6] = slog;
    __syncthreads();
    if (t == 0)
        ws[PART_OFF + blockIdx.x] = sh_red[0] + sh_red[1] + sh_red[2] + sh_red[3];
}

// ---------------- Kernel B: neg + log, folded to 256 columns ----------------
__global__ __launch_bounds__(256) void rnc_neg_kernel(
    const float* __restrict__ labels, float* __restrict__ ws)
{
    const int i = blockIdx.x;   // row 0..511
    const int t = threadIdx.x;  // k' = 0..255
    __shared__ float2 pr[256];  // {ld_j', E2[i][j']}
    __shared__ float  sh_red[4];

    const float lab_i = labels[i & 255];
    const float ldk   = fabsf(lab_i - labels[t]);
    // fold the two j-halves (exact: single 2-addend add, order-invariant)
    const float e2 = ws[E_OFF + i * 512 + t] + ws[E_OFF + i * 512 + t + 256];
    pr[t] = make_float2(ldk, e2);
    __syncthreads();

    float ng0 = 0, ng1 = 0, ng2 = 0, ng3 = 0;
    #pragma unroll 8
    for (int j = 0; j < 256; j += 4) {
        const float2 p0 = pr[j + 0], p1 = pr[j + 1];
        const float2 p2 = pr[j + 2], p3 = pr[j + 3];
        ng0 += (p0.x >= ldk) ? p0.y : 0.0f;
        ng1 += (p1.x >= ldk) ? p1.y : 0.0f;
        ng2 += (p2.x >= ldk) ? p2.y : 0.0f;
        ng3 += (p3.x >= ldk) ? p3.y : 0.0f;
    }
    const float neg = (ng0 + ng1) + (ng2 + ng3);
    // class k' = i&255 has 1 member among k != i, all other classes 2
    const float m = (t == (i & 255)) ? 1.0f : 2.0f;
    float partial = m * logf(neg);

    #pragma unroll
    for (int off = 32; off > 0; off >>= 1)
        partial += __shfl_xor(partial, off, 64);
    if ((t & 63) == 0) sh_red[t >> 6] = partial;
    __syncthreads();
    if (t == 0)
        ws[PART_OFF + 1024 + i] = sh_red[0] + sh_red[1] + sh_red[2] + sh_red[3];
}

// ---------------- Kernel C: final reduction ----------------
__global__ __launch_bounds__(256) void rnc_final_kernel(
    const float* __restrict__ ws, float* __restrict__ out)
{
    const int t = threadIdx.x;
    __shared__ float sa[4], sb[4];

    float sA = ws[PART_OFF + t] + ws[PART_OFF + t + 256] +
               ws[PART_OFF + t + 512] + ws[PART_OFF + t + 768];
    float sB = ws[PART_OFF + 1024 + t] + ws[PART_OFF + 1024 + t + 256];

    #pragma unroll
    for (int off = 32; off > 0; off >>= 1) {
        sA += __shfl_xor(sA, off, 64);
        sB += __shfl_xor(sB, off, 64);
    }
    if ((t & 63) == 0) { sa[t >> 6] = sA; sb[t >> 6] = sB; }
    __syncthreads();
    if (t == 0) {
        const float sumA = sa[0] + sa[1] + sa[2] + sa[3];  // sum of logits
        const float sumB = sb[0] + sb[1] + sb[2] + sb[3];  // sum of m*log(neg)
        out[0] = (sumB - sumA) * (1.0f / (512.0f * 511.0f));
    }
}

// ---------------- Fallback (round-1 fused kernel, needs no ws) ----------------
__global__ void init_out(float* out) { out[0] = 0.0f; }

__global__ __launch_bounds__(256) void rnc_row_kernel(
    const float* __restrict__ features, const float* __restrict__ labels,
    float* __restrict__ out)
{
    const int i = blockIdx.x;
    const int t = threadIdx.x;
    __shared__ float  sh_fi[D];
    __shared__ float2 sh_le[N];
    __shared__ float  sh_logit[N];
    __shared__ float  sh_red[4];

    const float* fi = frow(features, i);
    sh_fi[t] = fi[t];
    __syncthreads();
    const float lab_i = labels[i & 255];

    #pragma unroll
    for (int jj = 0; jj < 2; ++jj) {
        const int j = t + jj * 256;
        const float* fj = frow(features, j);
        float acc = 0.0f;
        #pragma unroll 4
        for (int d = 0; d < D; d += 4) {
            float4 v = *reinterpret_cast<const float4*>(fj + d);
            float d0 = sh_fi[d + 0] - v.x, d1 = sh_fi[d + 1] - v.y;
            float d2 = sh_fi[d + 2] - v.z, d3 = sh_fi[d + 3] - v.w;
            acc += d0 * d0 + d1 * d1 + d2 * d2 + d3 * d3;
        }
        float norm  = (acc > 0.0f) ? sqrtf(acc) : 0.0f;
        float logit = -norm * 0.5f;
        sh_logit[j] = logit;
        float e = (j == i) ? 0.0f : expf(logit);
        sh_le[j] = make_float2(fabsf(lab_i - labels[j & 255]), e);
    }
    __syncthreads();

    const int   k0 = t, k1 = t + 256;
    const float ldk0 = sh_le[k0].x, ldk1 = sh_le[k1].x;
    float neg0 = 0.0f, neg1 = 0.0f;
    #pragma unroll 8
    for (int j = 0; j < N; ++j) {
        float2 le = sh_le[j];
        neg0 += (le.x >= ldk0) ? le.y : 0.0f;
        neg1 += (le.x >= ldk1) ? le.y : 0.0f;
    }
    float partial = 0.0f;
    if (k0 != i) partial += sh_logit[k0] - logf(neg0);
    if (k1 != i) partial += sh_logit[k1] - logf(neg1);
    #pragma unroll
    for (int off = 32; off > 0; off >>= 1)
        partial += __shfl_down(partial, off, 64);
    if ((t & 63) == 0) sh_red[t >> 6] = partial;
    __syncthreads();
    if (t == 0)
        atomicAdd(out, (sh_red[0] + sh_red[1] + sh_red[2] + sh_red[3]) *
                       (-1.0f / ((float)N * (float)(N - 1))));
}

extern "C" void kernel_launch(void* const* d_in, const int* in_sizes, int n_in,
                              void* d_out, int out_size, void* d_ws, size_t ws_size,
                              hipStream_t stream) {
    const float* features = (const float*)d_in[0];  // (256, 2, 256) fp32
    const float* labels   = (const float*)d_in[1];  // (256, 1) fp32
    float* out = (float*)d_out;

    if (ws_size >= WS_BYTES) {
        float* ws = (float*)d_ws;
        rnc_dist_kernel<<<1024, 256, 0, stream>>>(features, ws);
        rnc_neg_kernel<<<512, 256, 0, stream>>>(labels, ws);
        rnc_final_kernel<<<1, 256, 0, stream>>>(ws, out);
    } else {
        init_out<<<1, 1, 0, stream>>>(out);
        rnc_row_kernel<<<N, 256, 0, stream>>>(features, labels, out);
    }
}